// Round 10
// baseline (57.951 us; speedup 1.0000x reference)
//
#include <hip/hip_runtime.h>

#define NTOK 16384
#define NC 2048
#define C4 512            // float4 per row
#define NE 8
#define TPB 256           // 4 waves
#define TOKW 8            // tokens per wave
#define TOK_PER_BLOCK 32  // 4 waves x 8 tokens
#define NBLK (NTOK / TOK_PER_BLOCK)   // 512

// Lore (R1-R9):
//  - VGPR cap = 256/launch_bounds_arg2: (256,2)->128 OK; (.,4)->64 -> spill disaster.
//  - acc MUST be separately-named arrays (acc[4][8] spilled, R5).
//  - Full k-unroll hoists all loads -> spill (R4). unroll 1 keeps 8 loads in flight.
//  - LDS gate staging (R9): -8us. ds_read+barrier not better than L1 hits.
//  - R6(32w/CU)==R8(16w/CU)==43-44us: not occupancy-bound, not gate-byte-bound.
//    R10 tests: gate VMEM-instruction share of the TA/L1 pipe (TOKW=8 halves it).
__global__ __launch_bounds__(TPB, 2) void router_kernel(
    const float* __restrict__ x, const float* __restrict__ gw,
    float* __restrict__ out, float* __restrict__ ws) {
    __shared__ float s_psum[NE];
    __shared__ float s_cnt[NE];

    const int tid = threadIdx.x;
    if (tid < NE) { s_psum[tid] = 0.0f; s_cnt[tid] = 0.0f; }
    __syncthreads();

    const int wave = tid >> 6;
    const int lane = tid & 63;
    const float4* x4 = (const float4*)x;
    const float4* gw4 = (const float4*)gw;
    const int t0 = blockIdx.x * TOK_PER_BLOCK + wave * TOKW;

    float* out_w = out;               // weights [N,2]
    float* out_i = out + 2 * NTOK;    // indices [N,2] stored as float

    float a0[NE], a1[NE], a2[NE], a3[NE], a4[NE], a5[NE], a6[NE], a7[NE];
    #pragma unroll
    for (int e = 0; e < NE; ++e) {
        a0[e] = 0.0f; a1[e] = 0.0f; a2[e] = 0.0f; a3[e] = 0.0f;
        a4[e] = 0.0f; a5[e] = 0.0f; a6[e] = 0.0f; a7[e] = 0.0f;
    }

    #pragma unroll 1
    for (int k = 0; k < 8; ++k) {
        const int idx = lane + k * 64;
        const float4 xv0 = x4[(size_t)(t0 + 0) * C4 + idx];   // coalesced 1KB/instr
        const float4 xv1 = x4[(size_t)(t0 + 1) * C4 + idx];
        const float4 xv2 = x4[(size_t)(t0 + 2) * C4 + idx];
        const float4 xv3 = x4[(size_t)(t0 + 3) * C4 + idx];
        const float4 xv4 = x4[(size_t)(t0 + 4) * C4 + idx];
        const float4 xv5 = x4[(size_t)(t0 + 5) * C4 + idx];
        const float4 xv6 = x4[(size_t)(t0 + 6) * C4 + idx];
        const float4 xv7 = x4[(size_t)(t0 + 7) * C4 + idx];
        #pragma unroll
        for (int e = 0; e < NE; ++e) {
            const float4 wv = gw4[e * C4 + idx];   // L1-resident (8KB active slice)
            a0[e] += xv0.x * wv.x + xv0.y * wv.y + xv0.z * wv.z + xv0.w * wv.w;
            a1[e] += xv1.x * wv.x + xv1.y * wv.y + xv1.z * wv.z + xv1.w * wv.w;
            a2[e] += xv2.x * wv.x + xv2.y * wv.y + xv2.z * wv.z + xv2.w * wv.w;
            a3[e] += xv3.x * wv.x + xv3.y * wv.y + xv3.z * wv.z + xv3.w * wv.w;
            a4[e] += xv4.x * wv.x + xv4.y * wv.y + xv4.z * wv.z + xv4.w * wv.w;
            a5[e] += xv5.x * wv.x + xv5.y * wv.y + xv5.z * wv.z + xv5.w * wv.w;
            a6[e] += xv6.x * wv.x + xv6.y * wv.y + xv6.z * wv.z + xv6.w * wv.w;
            a7[e] += xv7.x * wv.x + xv7.y * wv.y + xv7.z * wv.z + xv7.w * wv.w;
        }
    }

    // butterfly reduce over 64 lanes: every lane ends with full sums
    #pragma unroll
    for (int off = 32; off >= 1; off >>= 1) {
        #pragma unroll
        for (int e = 0; e < NE; ++e) {
            a0[e] += __shfl_xor(a0[e], off, 64);
            a1[e] += __shfl_xor(a1[e], off, 64);
            a2[e] += __shfl_xor(a2[e], off, 64);
            a3[e] += __shfl_xor(a3[e], off, 64);
            a4[e] += __shfl_xor(a4[e], off, 64);
            a5[e] += __shfl_xor(a5[e], off, 64);
            a6[e] += __shfl_xor(a6[e], off, 64);
            a7[e] += __shfl_xor(a7[e], off, 64);
        }
    }

    // lane processes token (lane&7) -- static select chain (rule #20)
    const int t = lane & 7;
    float l[NE];
    #pragma unroll
    for (int e = 0; e < NE; ++e) {
        float v = a0[e];
        v = (t == 1) ? a1[e] : v;
        v = (t == 2) ? a2[e] : v;
        v = (t == 3) ? a3[e] : v;
        v = (t == 4) ? a4[e] : v;
        v = (t == 5) ? a5[e] : v;
        v = (t == 6) ? a6[e] : v;
        v = (t == 7) ? a7[e] : v;
        l[e] = v;
    }

    float mx = l[0];
    #pragma unroll
    for (int e = 1; e < NE; ++e) mx = fmaxf(mx, l[e]);
    float p[NE];
    float s = 0.0f;
    #pragma unroll
    for (int e = 0; e < NE; ++e) { p[e] = expf(l[e] - mx); s += p[e]; }
    const float inv = 1.0f / s;
    #pragma unroll
    for (int e = 0; e < NE; ++e) p[e] *= inv;

    // top-2, ties -> lower index (matches jax.lax.top_k)
    int i0 = 0; float p0 = p[0];
    #pragma unroll
    for (int e = 1; e < NE; ++e) if (p[e] > p0) { p0 = p[e]; i0 = e; }
    int i1 = (i0 == 0) ? 1 : 0; float p1 = p[i1];
    #pragma unroll
    for (int e = 0; e < NE; ++e)
        if (e != i0 && p[e] > p1) { p1 = p[e]; i1 = e; }

    if (lane < TOKW) {
        const int token = t0 + lane;
        const float wsum = p0 + p1;
        out_w[2 * token]     = p0 / wsum;
        out_w[2 * token + 1] = p1 / wsum;
        out_i[2 * token]     = (float)i0;
        out_i[2 * token + 1] = (float)i1;

        #pragma unroll
        for (int e = 0; e < NE; ++e) atomicAdd(&s_psum[e], p[e]);
        atomicAdd(&s_cnt[i0], 1.0f);
        atomicAdd(&s_cnt[i1], 1.0f);
    }

    __syncthreads();
    // non-atomic per-block partials -> no zero-init kernel needed
    if (tid < NE)          ws[blockIdx.x * 16 + tid] = s_psum[tid];
    else if (tid < 2 * NE) ws[blockIdx.x * 16 + tid] = s_cnt[tid - NE];
}

__global__ void finalize_kernel(const float* __restrict__ ws,
                                float* __restrict__ out) {
    __shared__ float red[16];
    const int tid = threadIdx.x;   // 1024 threads
    if (tid < 16) red[tid] = 0.0f;
    __syncthreads();
    const int i = tid & 15;
    float sum = 0.0f;
    for (int b = (tid >> 4); b < NBLK; b += 64)
        sum += ws[b * 16 + i];
    atomicAdd(&red[i], sum);
    __syncthreads();
    if (tid == 0) {
        float aux = 0.0f;
        #pragma unroll
        for (int e = 0; e < NE; ++e)
            aux += (red[NE + e] * (1.0f / NTOK)) * (red[e] * (1.0f / NTOK));
        out[4 * NTOK] = (float)NE * aux;
    }
}

extern "C" void kernel_launch(void* const* d_in, const int* in_sizes, int n_in,
                              void* d_out, int out_size, void* d_ws, size_t ws_size,
                              hipStream_t stream) {
    const float* x  = (const float*)d_in[0];   // [4,4096,2048] f32
    const float* gw = (const float*)d_in[1];   // [8,2048] f32
    float* out = (float*)d_out;                // weights[N,2] | indices[N,2] | aux
    float* ws  = (float*)d_ws;                 // per-block partials [NBLK][16]

    router_kernel<<<NBLK, TPB, 0, stream>>>(x, gw, out, ws);
    finalize_kernel<<<1, 1024, 0, stream>>>(ws, out);
}

// Round 11
// 52.860 us; speedup vs baseline: 1.0963x; 1.0963x over previous
//
#include <hip/hip_runtime.h>

#define NTOK 16384
#define NC 2048
#define C4 512            // float4 per row
#define NE 8
#define TPB 256           // 4 waves
#define TOKW 2            // tokens per wave
#define TOK_PER_BLOCK 8   // 4 waves x 2 tokens
#define NBLK (NTOK / TOK_PER_BLOCK)   // 2048

// Lore (R1-R10):
//  - VGPR cap = 256/launch_bounds_arg2: (256,2)->128 OK; (.,4)->64 -> spill.
//  - acc/xv arrays: ALL indices must be compile-time (full unroll) or named.
//  - >=4096 waves required (R7/R10: 2048 waves -> +14us). R6==R8: beyond 4096
//    waves neutral; gate-byte halving neutral -> bound by per-CU line-fill
//    with shallow per-wave MLP. R11: hoist all 16 x-loads (64 VGPR in flight).
//  - R4 lesson: 32 hoisted loads (TOKW=4) = 128 regs -> spill. 16 loads fits.
//  - LDS gate staging (R9) regressed: L1 hits beat ds_read+barrier here.
__global__ __launch_bounds__(TPB, 2) void router_kernel(
    const float* __restrict__ x, const float* __restrict__ gw,
    float* __restrict__ out, float* __restrict__ ws) {
    __shared__ float s_psum[NE];
    __shared__ float s_cnt[NE];

    const int tid = threadIdx.x;
    if (tid < NE) { s_psum[tid] = 0.0f; s_cnt[tid] = 0.0f; }
    __syncthreads();

    const int wave = tid >> 6;
    const int lane = tid & 63;
    const float4* x4 = (const float4*)x;
    const float4* gw4 = (const float4*)gw;
    const int t0 = blockIdx.x * TOK_PER_BLOCK + wave * TOKW;

    float* out_w = out;               // weights [N,2]
    float* out_i = out + 2 * NTOK;    // indices [N,2] stored as float

    // ---- deep prefetch: ALL x loads in flight (16 x float4 = 64 VGPRs) ----
    float4 xv0[8], xv1[8];
    const float4* xr0 = x4 + (size_t)(t0 + 0) * C4 + lane;
    const float4* xr1 = x4 + (size_t)(t0 + 1) * C4 + lane;
    #pragma unroll
    for (int k = 0; k < 8; ++k) {
        xv0[k] = xr0[k * 64];
        xv1[k] = xr1[k * 64];
    }

    float acc0[NE], acc1[NE];
    #pragma unroll
    for (int e = 0; e < NE; ++e) { acc0[e] = 0.0f; acc1[e] = 0.0f; }

    #pragma unroll
    for (int k = 0; k < 8; ++k) {
        const int idx = lane + k * 64;
        #pragma unroll
        for (int e = 0; e < NE; ++e) {
            const float4 wv = gw4[e * C4 + idx];   // L1-resident hot slice
            acc0[e] += xv0[k].x * wv.x + xv0[k].y * wv.y +
                       xv0[k].z * wv.z + xv0[k].w * wv.w;
            acc1[e] += xv1[k].x * wv.x + xv1[k].y * wv.y +
                       xv1[k].z * wv.z + xv1[k].w * wv.w;
        }
    }

    // butterfly reduce over 64 lanes: every lane ends with full sums
    #pragma unroll
    for (int off = 32; off >= 1; off >>= 1) {
        #pragma unroll
        for (int e = 0; e < NE; ++e) {
            acc0[e] += __shfl_xor(acc0[e], off, 64);
            acc1[e] += __shfl_xor(acc1[e], off, 64);
        }
    }

    // lane processes token (lane&1) -- static select (rule #20)
    const int t = lane & 1;
    float l[NE];
    #pragma unroll
    for (int e = 0; e < NE; ++e) l[e] = t ? acc1[e] : acc0[e];

    float mx = l[0];
    #pragma unroll
    for (int e = 1; e < NE; ++e) mx = fmaxf(mx, l[e]);
    float p[NE];
    float s = 0.0f;
    #pragma unroll
    for (int e = 0; e < NE; ++e) { p[e] = expf(l[e] - mx); s += p[e]; }
    const float inv = 1.0f / s;
    #pragma unroll
    for (int e = 0; e < NE; ++e) p[e] *= inv;

    // top-2, ties -> lower index (matches jax.lax.top_k)
    int i0 = 0; float p0 = p[0];
    #pragma unroll
    for (int e = 1; e < NE; ++e) if (p[e] > p0) { p0 = p[e]; i0 = e; }
    int i1 = (i0 == 0) ? 1 : 0; float p1 = p[i1];
    #pragma unroll
    for (int e = 0; e < NE; ++e)
        if (e != i0 && p[e] > p1) { p1 = p[e]; i1 = e; }

    if (lane < TOKW) {
        const int token = t0 + lane;
        const float wsum = p0 + p1;
        out_w[2 * token]     = p0 / wsum;
        out_w[2 * token + 1] = p1 / wsum;
        out_i[2 * token]     = (float)i0;
        out_i[2 * token + 1] = (float)i1;

        #pragma unroll
        for (int e = 0; e < NE; ++e) atomicAdd(&s_psum[e], p[e]);
        atomicAdd(&s_cnt[i0], 1.0f);
        atomicAdd(&s_cnt[i1], 1.0f);
    }

    __syncthreads();
    // non-atomic per-block partials -> no zero-init kernel needed
    if (tid < NE)          ws[blockIdx.x * 16 + tid] = s_psum[tid];
    else if (tid < 2 * NE) ws[blockIdx.x * 16 + tid] = s_cnt[tid - NE];
}

__global__ void finalize_kernel(const float* __restrict__ ws,
                                float* __restrict__ out) {
    __shared__ float red[16];
    const int tid = threadIdx.x;   // 1024 threads
    if (tid < 16) red[tid] = 0.0f;
    __syncthreads();
    const int i = tid & 15;
    float sum = 0.0f;
    for (int b = (tid >> 4); b < NBLK; b += 64)
        sum += ws[b * 16 + i];
    atomicAdd(&red[i], sum);
    __syncthreads();
    if (tid == 0) {
        float aux = 0.0f;
        #pragma unroll
        for (int e = 0; e < NE; ++e)
            aux += (red[NE + e] * (1.0f / NTOK)) * (red[e] * (1.0f / NTOK));
        out[4 * NTOK] = (float)NE * aux;
    }
}

extern "C" void kernel_launch(void* const* d_in, const int* in_sizes, int n_in,
                              void* d_out, int out_size, void* d_ws, size_t ws_size,
                              hipStream_t stream) {
    const float* x  = (const float*)d_in[0];   // [4,4096,2048] f32
    const float* gw = (const float*)d_in[1];   // [8,2048] f32
    float* out = (float*)d_out;                // weights[N,2] | indices[N,2] | aux
    float* ws  = (float*)d_ws;                 // per-block partials [NBLK][16]

    router_kernel<<<NBLK, TPB, 0, stream>>>(x, gw, out, ws);
    finalize_kernel<<<1, 1024, 0, stream>>>(ws, out);
}